// Round 1
// baseline (851.542 us; speedup 1.0000x reference)
//
#include <hip/hip_runtime.h>
#include <hip/hip_bf16.h>
#include <stdint.h>

#define N_PTS   262144
#define H_DIM   512
#define W_DIM   512
#define N_SEG   16
#define EPS_V   1e-5f

typedef __bf16 bf16_t;
typedef __bf16 bf16x8 __attribute__((ext_vector_type(8)));
typedef float  f32x4  __attribute__((ext_vector_type(4)));

// ------------- workspace layouts -------------
// FUSED+SORT (ws >= ~140.2 MB):
//   idx_map int[4*512*512]            @ 0            (4194304)   packed (seg<<18)|idx, -1 empty
//   cat     bf16[(N+1)*256]           @ 4194304      (134218240) [feat|h1|h2|h3], row N = zeros
//   wfrag   bf16[258048]              @ 138412544    (516096)
//   stats   float[12416]              @ 138928640    (49664)
//   hist    int[4096]                 @ stats+12416f
//   cursor  int[4096]
//   ord     int[N]                    (new->old point permutation, tile-sorted)
// FUSED (ws >= 139 MB): same minus hist/cursor/ord (ord = nullptr)
// FALLBACK: as before at 72 MB.
// stats block (floats): cnt[16]@0 ymin@16 ymax@32 xmin@48 xmax@64 dseg[48]@80
//   sums[3*1024]@128 sumsq[3*1024]@3200 pA[3*1024]@6272 pB[3*1024]@9344

__global__ void init_kernel(int* cnt, int* ymin, int* ymax, int* xmin, int* xmax,
                            float* sums, float* sumsq, int* hist) {
  int t = threadIdx.x;
  if (t < N_SEG) {
    cnt[t] = 0;
    ymin[t] = 0x7fffffff; ymax[t] = (int)0x80000000;
    xmin[t] = 0x7fffffff; xmax[t] = (int)0x80000000;
  }
  for (int i = t; i < 3 * 1024; i += 256) { sums[i] = 0.f; sumsq[i] = 0.f; }
  if (hist) for (int i = t; i < 4096; i += 256) hist[i] = 0;
}

__global__ void scatter_kernel(const int* __restrict__ indices,
                               const int* __restrict__ seg,
                               int* __restrict__ idx_map,
                               int* __restrict__ cnt,
                               int* __restrict__ ymin, int* __restrict__ ymax,
                               int* __restrict__ xmin, int* __restrict__ xmax,
                               int* __restrict__ hist) {
  __shared__ int lc[N_SEG], ly0[N_SEG], ly1[N_SEG], lx0[N_SEG], lx1[N_SEG];
  int tid = threadIdx.x;
  if (tid < N_SEG) {
    lc[tid] = 0;
    ly0[tid] = 0x7fffffff; ly1[tid] = (int)0x80000000;
    lx0[tid] = 0x7fffffff; lx1[tid] = (int)0x80000000;
  }
  __syncthreads();
  int i = blockIdx.x * 256 + tid;
  int b = indices[i * 3], y = indices[i * 3 + 1], x = indices[i * 3 + 2];
  int s = seg[i];
  idx_map[(b * H_DIM + y) * W_DIM + x] = (s << 18) | i;   // packed seg+idx
  atomicAdd(&lc[s], 1);
  atomicMin(&ly0[s], y); atomicMax(&ly1[s], y);
  atomicMin(&lx0[s], x); atomicMax(&lx1[s], x);
  if (hist) {
    int key = (b << 10) | ((y >> 4) << 5) | (x >> 4);     // 4096 spatial tiles
    atomicAdd(&hist[key], 1);
  }
  __syncthreads();
  if (tid < N_SEG && lc[tid] > 0) {
    atomicAdd(&cnt[tid], lc[tid]);
    atomicMin(&ymin[tid], ly0[tid]); atomicMax(&ymax[tid], ly1[tid]);
    atomicMin(&xmin[tid], lx0[tid]); atomicMax(&xmax[tid], lx1[tid]);
  }
}

// exclusive prefix sum of hist[4096] -> cursor[4096]
__global__ void scan_kernel(const int* __restrict__ hist, int* __restrict__ cursor) {
  __shared__ int s[256];
  int t = threadIdx.x;
  int base = t * 16;
  int loc[16];
  int acc = 0;
#pragma unroll
  for (int j = 0; j < 16; ++j) { loc[j] = acc; acc += hist[base + j]; }
  s[t] = acc;
  __syncthreads();
  for (int o = 1; o < 256; o <<= 1) {
    int v = (t >= o) ? s[t - o] : 0;
    __syncthreads();
    s[t] += v;
    __syncthreads();
  }
  int pre = (t == 0) ? 0 : s[t - 1];
#pragma unroll
  for (int j = 0; j < 16; ++j) cursor[base + j] = pre + loc[j];
}

__global__ void rank_kernel(const int* __restrict__ indices,
                            int* __restrict__ cursor, int* __restrict__ ord) {
  int i = blockIdx.x * 256 + threadIdx.x;
  int b = indices[i * 3], y = indices[i * 3 + 1], x = indices[i * 3 + 2];
  int key = (b << 10) | ((y >> 4) << 5) | (x >> 4);
  int pos = atomicAdd(&cursor[key], 1);
  ord[pos] = i;
}

__global__ void dilation_kernel(const int* ymin, const int* ymax,
                                const int* xmin, const int* xmax,
                                const int* cnt, int* dseg) {
  int t = threadIdx.x;
  if (t < 48) {
    int r = t >> 4, s = t & 15;
    int rate = (r == 0) ? 1 : (r == 1) ? 3 : 5;
    int d = 1;
    if (cnt[s] > 0) {
      float hr = (float)(ymax[s] - ymin[s]) * (1.0f / H_DIM);
      float wr = (float)(xmax[s] - xmin[s]) * (1.0f / W_DIM);
      d = (int)ceilf(fmaxf(hr, wr) * (float)rate);
      if (d < 1) d = 1;
    }
    dseg[t] = d;
  }
}

// features fp32 -> bf16 rows of a strided buffer
__global__ void convert_kernel(const float4* __restrict__ in, bf16_t* __restrict__ dst,
                               int stride) {
  int i = blockIdx.x * 256 + threadIdx.x;   // N*16
  int pt = i >> 4, g = i & 15;
  float4 v = in[i];
  union { bf16_t h[4]; uint2 u; } o;
  o.h[0] = (bf16_t)v.x; o.h[1] = (bf16_t)v.y;
  o.h[2] = (bf16_t)v.z; o.h[3] = (bf16_t)v.w;
  *(uint2*)(dst + (size_t)pt * stride + g * 4) = o.u;
}

// wfrag: [0,110592): branch r in {0,1,2} at r*36864, layout [k][kk2][cot][lane][j]
//        [110592,258048): fused final, layout [k][kk8][cot][lane][j], kk8=0..7
__global__ void repack_kernel(const float* __restrict__ w1, const float* __restrict__ w2,
                              const float* __restrict__ w3, const float* __restrict__ wf,
                              bf16_t* __restrict__ wfrag) {
  int e = blockIdx.x * 256 + threadIdx.x;   // < 258048
  if (e < 110592) {
    int s = e / 36864, rem = e % 36864;
    int k = rem >> 12, r2 = rem & 4095;
    int kk = r2 >> 11, r3 = r2 & 2047;
    int cot = r3 >> 9, r4 = r3 & 511;
    int lane = r4 >> 3, j = r4 & 7;
    int c  = kk * 32 + (lane >> 4) * 8 + j;
    int co = cot * 16 + (lane & 15);
    const float* w = (s == 0) ? w1 : (s == 1) ? w2 : w3;
    wfrag[e] = (bf16_t)w[k * 4096 + c * 64 + co];
  } else {
    int ef = e - 110592;
    int k = ef >> 14, r2 = ef & 16383;
    int kk8 = r2 >> 11, r3 = r2 & 2047;
    int cot = r3 >> 9, r4 = r3 & 511;
    int lane = r4 >> 3, j = r4 & 7;
    int c  = kk8 * 32 + (lane >> 4) * 8 + j;   // 0..255
    int co = cot * 16 + (lane & 15);
    wfrag[e] = (bf16_t)wf[k * 16384 + c * 64 + co];
  }
}

// KK: number of 32-ch K-slices per neighbor (2 = 64ch, 8 = 256ch)
// MODE 0: branch conv (same-seg mask + dilation) -> bf16 outh slice
// MODE 1: final conv, out = acc + bias
// MODE 2: final conv accumulate pass (fallback), out += acc
// ord: optional new->old point permutation (tile-sorted). Data stays in
//      ORIGINAL order; only the block->point assignment changes, so gathers
//      within a block hit a ~50 KB spatially-local working set (L2-resident).
template <int KK, int MODE>
__launch_bounds__(256)
__global__ void conv_mfma(const bf16_t* __restrict__ A, int astride,
                          const bf16_t* __restrict__ wfrag, int wkstride,
                          const int* __restrict__ indices,
                          const int* __restrict__ seg,
                          const int* __restrict__ idx_map,
                          const int* __restrict__ dseg,
                          const int* __restrict__ ord,
                          float* __restrict__ outf,
                          bf16_t* __restrict__ outh, int hstride, int hoff,
                          const float* __restrict__ bias) {
  __shared__ int s_nbr[9 * 64];
  __shared__ int s_pt[64], s_b[64], s_y[64], s_x[64], s_sg[64], s_d[64];
  const int tid = threadIdx.x;
  int bid = blockIdx.x;
  // XCD-chunk swizzle (bijective: gridDim.x == 4096, 4096 % 8 == 0): with
  // tile-sorted ord, consecutive tiles land on the same XCD's L2.
  if (ord) bid = (bid & 7) * ((int)gridDim.x >> 3) + (bid >> 3);
  const int pt0 = bid * 64;

  if (tid < 64) {
    int pt = ord ? ord[pt0 + tid] : (pt0 + tid);
    s_pt[tid] = pt;
    s_b[tid] = indices[pt * 3];
    s_y[tid] = indices[pt * 3 + 1];
    s_x[tid] = indices[pt * 3 + 2];
    int sg = 0, d = 1;
    if (MODE == 0) { sg = seg[pt]; d = dseg[sg]; }
    s_sg[tid] = sg; s_d[tid] = d;
  }
  __syncthreads();

  for (int e = tid; e < 576; e += 256) {
    int k = e >> 6, row = e & 63;
    int ky = (k / 3) - 1, kx = (k % 3) - 1;
    int d = s_d[row];
    int ny = s_y[row] + ky * d, nx = s_x[row] + kx * d;
    int nbr = N_PTS;                           // sentinel zero row
    if (ny >= 0 && ny < H_DIM && nx >= 0 && nx < W_DIM) {
      int v = idx_map[(s_b[row] * H_DIM + ny) * W_DIM + nx];
      if (v >= 0) {                            // packed (seg<<18)|idx
        if (MODE == 0) nbr = ((v >> 18) == s_sg[row]) ? (v & 0x3FFFF) : N_PTS;
        else           nbr = v & 0x3FFFF;
      }
    }
    s_nbr[e] = nbr;
  }
  __syncthreads();

  const int lane = tid & 63;
  const int wv = tid >> 6;
  const int m = lane & 15;
  const int quad = lane >> 4;
  const int rowm = wv * 16 + m;

  f32x4 acc[4];
#pragma unroll
  for (int c = 0; c < 4; ++c) { acc[c][0] = 0.f; acc[c][1] = 0.f; acc[c][2] = 0.f; acc[c][3] = 0.f; }

  if constexpr (KK == 2) {
    // batch ALL 18 A-fragment gathers before the MFMA chain (max MLP)
    bf16x8 a[9][2];
#pragma unroll
    for (int k = 0; k < 9; ++k) {
      const bf16_t* ar = A + (size_t)s_nbr[k * 64 + rowm] * astride + quad * 8;
      a[k][0] = *(const bf16x8*)(ar);
      a[k][1] = *(const bf16x8*)(ar + 32);
    }
#pragma unroll
    for (int k = 0; k < 9; ++k) {
#pragma unroll
      for (int kk = 0; kk < 2; ++kk) {
        const bf16_t* wb = wfrag + k * wkstride + kk * 2048 + lane * 8;
#pragma unroll
        for (int cot = 0; cot < 4; ++cot)
          acc[cot] = __builtin_amdgcn_mfma_f32_16x16x32_bf16(
              a[k][kk], *(const bf16x8*)(wb + cot * 512), acc[cot], 0, 0, 0);
      }
    }
  } else {
    // KK == 8: double-buffer A over neighbors (8 loads in flight)
    bf16x8 a[2][8];
    {
      const bf16_t* ar = A + (size_t)s_nbr[rowm] * astride + quad * 8;
#pragma unroll
      for (int kk = 0; kk < 8; ++kk) a[0][kk] = *(const bf16x8*)(ar + kk * 32);
    }
#pragma unroll
    for (int k = 0; k < 9; ++k) {
      const int cur = k & 1, nxt = cur ^ 1;
      if (k < 8) {
        const bf16_t* ar = A + (size_t)s_nbr[(k + 1) * 64 + rowm] * astride + quad * 8;
#pragma unroll
        for (int kk = 0; kk < 8; ++kk) a[nxt][kk] = *(const bf16x8*)(ar + kk * 32);
      }
#pragma unroll
      for (int kk = 0; kk < 8; ++kk) {
        const bf16_t* wb = wfrag + k * wkstride + kk * 2048 + lane * 8;
#pragma unroll
        for (int cot = 0; cot < 4; ++cot)
          acc[cot] = __builtin_amdgcn_mfma_f32_16x16x32_bf16(
              a[cur][kk], *(const bf16x8*)(wb + cot * 512), acc[cot], 0, 0, 0);
      }
    }
  }

#pragma unroll
  for (int reg = 0; reg < 4; ++reg) {
    int r = wv * 16 + quad * 4 + reg;
    int pt = s_pt[r];
#pragma unroll
    for (int cot = 0; cot < 4; ++cot) {
      int col = cot * 16 + m;
      float v = acc[cot][reg];
      if (MODE == 0)      outh[(size_t)pt * hstride + hoff + col] = (bf16_t)v;
      else if (MODE == 1) outf[(size_t)pt * 64 + col] = v + bias[col];
      else                outf[(size_t)pt * 64 + col] += v;
    }
  }
}

__global__ void stats_kernel(const bf16_t* __restrict__ h, int stride, int off,
                             const int* __restrict__ seg,
                             float* __restrict__ sums, float* __restrict__ sumsq) {
  int tid = threadIdx.x;
  int co = tid & 63, pr = tid >> 6;
  int base = blockIdx.x * 1024;
  float s = 0.f, s2 = 0.f;
  int cur = seg[base];
  for (int i = pr; i < 1024; i += 4) {
    int pt = base + i;
    int sg = seg[pt];
    float v = (float)h[(size_t)pt * stride + off + co];
    if (sg != cur) {
      atomicAdd(&sums[cur * 64 + co], s);
      atomicAdd(&sumsq[cur * 64 + co], s2);
      s = 0.f; s2 = 0.f; cur = sg;
    }
    s += v; s2 += v * v;
  }
  atomicAdd(&sums[cur * 64 + co], s);
  atomicAdd(&sumsq[cur * 64 + co], s2);
}

__global__ void params_kernel(const int* __restrict__ cnt, const float* __restrict__ sums,
                              const float* __restrict__ sumsq,
                              float* __restrict__ pA, float* __restrict__ pB) {
  int t = blockIdx.x * 256 + threadIdx.x;
  if (t < 1024) {
    int sgi = t >> 6;
    float c = (float)cnt[sgi];
    float a = 0.f, b = 0.f;
    if (c > 0.f) {
      float mean = sums[t] / c;
      float var = sumsq[t] / c - mean * mean;
      float inv = rsqrtf(var + EPS_V);
      a = inv; b = -mean * inv;
    }
    pA[t] = a; pB[t] = b;
  }
}

__global__ void norm_kernel(bf16_t* __restrict__ h, int stride, int off,
                            const int* __restrict__ seg,
                            const float* __restrict__ pA, const float* __restrict__ pB) {
  int i = blockIdx.x * 256 + threadIdx.x;   // N*16
  int pt = i >> 4;
  int cg = (i & 15) * 4;
  int sg = seg[pt];
  bf16_t* p = h + (size_t)pt * stride + off + cg;
  union { bf16_t hh[4]; uint2 u; } v;
  v.u = *(uint2*)p;
#pragma unroll
  for (int j = 0; j < 4; ++j) {
    float f = (float)v.hh[j] * pA[sg * 64 + cg + j] + pB[sg * 64 + cg + j];
    v.hh[j] = (bf16_t)fmaxf(f, 0.f);
  }
  *(uint2*)p = v.u;
}

extern "C" void kernel_launch(void* const* d_in, const int* in_sizes, int n_in,
                              void* d_out, int out_size, void* d_ws, size_t ws_size,
                              hipStream_t stream) {
  const float* feats   = (const float*)d_in[0];
  const int*   indices = (const int*)d_in[1];
  const int*   seg     = (const int*)d_in[2];
  const float* w1 = (const float*)d_in[3];
  const float* w2 = (const float*)d_in[5];
  const float* w3 = (const float*)d_in[7];
  const float* wf = (const float*)d_in[9];
  const float* bf_ = (const float*)d_in[10];
  float* out = (float*)d_out;

  char* ws = (char*)d_ws;
  const bool sorted = (ws_size >= 140200000ull);
  const bool fused  = sorted || (ws_size >= 139000000ull);

  int* idx_map = (int*)(ws + 0);
  hipMemsetAsync(idx_map, 0xFF, 4194304, stream);

  if (fused) {
    bf16_t* cat   = (bf16_t*)(ws + 4194304);           // (N+1) x 256
    bf16_t* wfrag = (bf16_t*)(ws + 138412544);
    float*  stats = (float*)(ws + 138928640);
    int* cnt  = (int*)stats;
    int* ymin = (int*)(stats + 16);
    int* ymax = (int*)(stats + 32);
    int* xmin = (int*)(stats + 48);
    int* xmax = (int*)(stats + 64);
    int* dseg = (int*)(stats + 80);
    float* sums  = stats + 128;
    float* sumsq = stats + 3200;
    float* pA    = stats + 6272;
    float* pB    = stats + 9344;
    int* hist   = sorted ? (int*)(stats + 12416) : nullptr;
    int* cursor = sorted ? hist + 4096 : nullptr;
    int* ord    = sorted ? hist + 8192 : nullptr;      // int[N]

    hipMemsetAsync(cat + (size_t)N_PTS * 256, 0, 512, stream);   // sentinel row
    init_kernel<<<1, 256, 0, stream>>>(cnt, ymin, ymax, xmin, xmax, sums, sumsq, hist);
    scatter_kernel<<<N_PTS / 256, 256, 0, stream>>>(indices, seg, idx_map, cnt, ymin, ymax, xmin, xmax, hist);
    dilation_kernel<<<1, 64, 0, stream>>>(ymin, ymax, xmin, xmax, cnt, dseg);
    if (sorted) {
      scan_kernel<<<1, 256, 0, stream>>>(hist, cursor);
      rank_kernel<<<N_PTS / 256, 256, 0, stream>>>(indices, cursor, ord);
    }
    convert_kernel<<<16384, 256, 0, stream>>>((const float4*)feats, cat, 256);
    repack_kernel<<<1008, 256, 0, stream>>>(w1, w2, w3, wf, wfrag);

    for (int r = 0; r < 3; ++r) {
      conv_mfma<2, 0><<<4096, 256, 0, stream>>>(cat, 256, wfrag + (size_t)r * 36864, 4096,
                                                indices, seg, idx_map, dseg + r * 16, ord,
                                                nullptr, cat, 256, (r + 1) * 64, nullptr);
      stats_kernel<<<256, 256, 0, stream>>>(cat, 256, (r + 1) * 64, seg,
                                            sums + r * 1024, sumsq + r * 1024);
      params_kernel<<<4, 256, 0, stream>>>(cnt, sums + r * 1024, sumsq + r * 1024,
                                           pA + r * 1024, pB + r * 1024);
      norm_kernel<<<16384, 256, 0, stream>>>(cat, 256, (r + 1) * 64, seg,
                                             pA + r * 1024, pB + r * 1024);
    }
    // fused final conv: K = 256 in one pass
    conv_mfma<8, 1><<<4096, 256, 0, stream>>>(cat, 256, wfrag + 110592, 16384,
                                              indices, seg, idx_map, nullptr, ord,
                                              out, nullptr, 0, 0, bf_);
  } else {
    bf16_t* feats_bf = (bf16_t*)(ws + 4194304);        // (N+1) x 64
    bf16_t* h_bf     = (bf16_t*)(ws + 37748864);       // (N+1) x 64
    bf16_t* wfrag    = (bf16_t*)(ws + 71303424);
    float*  stats    = (float*)(ws + 71819520);
    int* cnt  = (int*)stats;
    int* ymin = (int*)(stats + 16);
    int* ymax = (int*)(stats + 32);
    int* xmin = (int*)(stats + 48);
    int* xmax = (int*)(stats + 64);
    int* dseg = (int*)(stats + 80);
    float* sums  = stats + 128;
    float* sumsq = stats + 3200;
    float* pA    = stats + 6272;
    float* pB    = stats + 9344;

    hipMemsetAsync(feats_bf + (size_t)N_PTS * 64, 0, 128, stream);
    hipMemsetAsync(h_bf + (size_t)N_PTS * 64, 0, 128, stream);
    init_kernel<<<1, 256, 0, stream>>>(cnt, ymin, ymax, xmin, xmax, sums, sumsq, nullptr);
    scatter_kernel<<<N_PTS / 256, 256, 0, stream>>>(indices, seg, idx_map, cnt, ymin, ymax, xmin, xmax, nullptr);
    dilation_kernel<<<1, 64, 0, stream>>>(ymin, ymax, xmin, xmax, cnt, dseg);
    convert_kernel<<<16384, 256, 0, stream>>>((const float4*)feats, feats_bf, 64);
    repack_kernel<<<1008, 256, 0, stream>>>(w1, w2, w3, wf, wfrag);

    // final conv pass 0: features slice (init with bias), uses fused-wfrag slice p=0
    conv_mfma<2, 1><<<4096, 256, 0, stream>>>(feats_bf, 64, wfrag + 110592, 16384,
                                              indices, seg, idx_map, nullptr, nullptr,
                                              out, nullptr, 0, 0, bf_);
    for (int r = 0; r < 3; ++r) {
      conv_mfma<2, 0><<<4096, 256, 0, stream>>>(feats_bf, 64, wfrag + (size_t)r * 36864, 4096,
                                                indices, seg, idx_map, dseg + r * 16, nullptr,
                                                nullptr, h_bf, 64, 0, nullptr);
      stats_kernel<<<256, 256, 0, stream>>>(h_bf, 64, 0, seg, sums + r * 1024, sumsq + r * 1024);
      params_kernel<<<4, 256, 0, stream>>>(cnt, sums + r * 1024, sumsq + r * 1024,
                                           pA + r * 1024, pB + r * 1024);
      norm_kernel<<<16384, 256, 0, stream>>>(h_bf, 64, 0, seg, pA + r * 1024, pB + r * 1024);
      conv_mfma<2, 2><<<4096, 256, 0, stream>>>(h_bf, 64, wfrag + 110592 + (size_t)(r + 1) * 4096, 16384,
                                                indices, seg, idx_map, nullptr, nullptr,
                                                out, nullptr, 0, 0, nullptr);
    }
  }
}

// Round 2
// 786.042 us; speedup vs baseline: 1.0833x; 1.0833x over previous
//
#include <hip/hip_runtime.h>
#include <hip/hip_bf16.h>
#include <stdint.h>

#define N_PTS   262144
#define H_DIM   512
#define W_DIM   512
#define N_SEG   16
#define EPS_V   1e-5f

typedef __bf16 bf16_t;
typedef __bf16 bf16x8 __attribute__((ext_vector_type(8)));
typedef float  f32x4  __attribute__((ext_vector_type(4)));

// ------------- workspace layouts -------------
// FUSED+SORT (ws >= ~140.2 MB):
//   idx_map int[4*512*512]            @ 0            (4194304)   packed (seg<<18)|idx, -1 empty
//   cat     bf16[(N+1)*256]           @ 4194304      (134218240) [feat|h1|h2|h3], row N = zeros
//   wfrag   bf16[258048]              @ 138412544    (516096)
//   stats   float[12416]              @ 138928640    (49664)
//   hist    int[4096] / cursor int[4096] / ord int[N]
// FUSED (ws >= 139 MB): same minus hist/cursor/ord (ord = nullptr)
// FALLBACK: as before at 72 MB.
// stats block (floats): cnt[16]@0 ymin@16 ymax@32 xmin@48 xmax@64 dseg[48]@80
//   sums[3*1024]@128 sumsq[3*1024]@3200 pA[3*1024]@6272 pB[3*1024]@9344

__global__ void init_kernel(int* cnt, int* ymin, int* ymax, int* xmin, int* xmax,
                            float* sums, float* sumsq, int* hist) {
  int t = threadIdx.x;
  if (t < N_SEG) {
    cnt[t] = 0;
    ymin[t] = 0x7fffffff; ymax[t] = (int)0x80000000;
    xmin[t] = 0x7fffffff; xmax[t] = (int)0x80000000;
  }
  for (int i = t; i < 3 * 1024; i += 256) { sums[i] = 0.f; sumsq[i] = 0.f; }
  if (hist) for (int i = t; i < 4096; i += 256) hist[i] = 0;
}

__global__ void scatter_kernel(const int* __restrict__ indices,
                               const int* __restrict__ seg,
                               int* __restrict__ idx_map,
                               int* __restrict__ cnt,
                               int* __restrict__ ymin, int* __restrict__ ymax,
                               int* __restrict__ xmin, int* __restrict__ xmax,
                               int* __restrict__ hist) {
  __shared__ int lc[N_SEG], ly0[N_SEG], ly1[N_SEG], lx0[N_SEG], lx1[N_SEG];
  int tid = threadIdx.x;
  if (tid < N_SEG) {
    lc[tid] = 0;
    ly0[tid] = 0x7fffffff; ly1[tid] = (int)0x80000000;
    lx0[tid] = 0x7fffffff; lx1[tid] = (int)0x80000000;
  }
  __syncthreads();
  int i = blockIdx.x * 256 + tid;
  int b = indices[i * 3], y = indices[i * 3 + 1], x = indices[i * 3 + 2];
  int s = seg[i];
  idx_map[(b * H_DIM + y) * W_DIM + x] = (s << 18) | i;   // packed seg+idx
  atomicAdd(&lc[s], 1);
  atomicMin(&ly0[s], y); atomicMax(&ly1[s], y);
  atomicMin(&lx0[s], x); atomicMax(&lx1[s], x);
  if (hist) {
    int key = (b << 10) | ((y >> 4) << 5) | (x >> 4);     // 4096 spatial tiles
    atomicAdd(&hist[key], 1);
  }
  __syncthreads();
  if (tid < N_SEG && lc[tid] > 0) {
    atomicAdd(&cnt[tid], lc[tid]);
    atomicMin(&ymin[tid], ly0[tid]); atomicMax(&ymax[tid], ly1[tid]);
    atomicMin(&xmin[tid], lx0[tid]); atomicMax(&xmax[tid], lx1[tid]);
  }
}

// exclusive prefix sum of hist[4096] -> cursor[4096]
__global__ void scan_kernel(const int* __restrict__ hist, int* __restrict__ cursor) {
  __shared__ int s[256];
  int t = threadIdx.x;
  int base = t * 16;
  int loc[16];
  int acc = 0;
#pragma unroll
  for (int j = 0; j < 16; ++j) { loc[j] = acc; acc += hist[base + j]; }
  s[t] = acc;
  __syncthreads();
  for (int o = 1; o < 256; o <<= 1) {
    int v = (t >= o) ? s[t - o] : 0;
    __syncthreads();
    s[t] += v;
    __syncthreads();
  }
  int pre = (t == 0) ? 0 : s[t - 1];
#pragma unroll
  for (int j = 0; j < 16; ++j) cursor[base + j] = pre + loc[j];
}

__global__ void rank_kernel(const int* __restrict__ indices,
                            int* __restrict__ cursor, int* __restrict__ ord) {
  int i = blockIdx.x * 256 + threadIdx.x;
  int b = indices[i * 3], y = indices[i * 3 + 1], x = indices[i * 3 + 2];
  int key = (b << 10) | ((y >> 4) << 5) | (x >> 4);
  int pos = atomicAdd(&cursor[key], 1);
  ord[pos] = i;
}

__global__ void dilation_kernel(const int* ymin, const int* ymax,
                                const int* xmin, const int* xmax,
                                const int* cnt, int* dseg) {
  int t = threadIdx.x;
  if (t < 48) {
    int r = t >> 4, s = t & 15;
    int rate = (r == 0) ? 1 : (r == 1) ? 3 : 5;
    int d = 1;
    if (cnt[s] > 0) {
      float hr = (float)(ymax[s] - ymin[s]) * (1.0f / H_DIM);
      float wr = (float)(xmax[s] - xmin[s]) * (1.0f / W_DIM);
      d = (int)ceilf(fmaxf(hr, wr) * (float)rate);
      if (d < 1) d = 1;
    }
    dseg[t] = d;
  }
}

// features fp32 -> bf16 rows of a strided buffer
__global__ void convert_kernel(const float4* __restrict__ in, bf16_t* __restrict__ dst,
                               int stride) {
  int i = blockIdx.x * 256 + threadIdx.x;   // N*16
  int pt = i >> 4, g = i & 15;
  float4 v = in[i];
  union { bf16_t h[4]; uint2 u; } o;
  o.h[0] = (bf16_t)v.x; o.h[1] = (bf16_t)v.y;
  o.h[2] = (bf16_t)v.z; o.h[3] = (bf16_t)v.w;
  *(uint2*)(dst + (size_t)pt * stride + g * 4) = o.u;
}

// wfrag: [0,110592): branch r in {0,1,2} at r*36864, layout [k][kk2][cot][lane][j]
//        [110592,258048): fused final, layout [k][kk8][cot][lane][j], kk8=0..7
__global__ void repack_kernel(const float* __restrict__ w1, const float* __restrict__ w2,
                              const float* __restrict__ w3, const float* __restrict__ wf,
                              bf16_t* __restrict__ wfrag) {
  int e = blockIdx.x * 256 + threadIdx.x;   // < 258048
  if (e < 110592) {
    int s = e / 36864, rem = e % 36864;
    int k = rem >> 12, r2 = rem & 4095;
    int kk = r2 >> 11, r3 = r2 & 2047;
    int cot = r3 >> 9, r4 = r3 & 511;
    int lane = r4 >> 3, j = r4 & 7;
    int c  = kk * 32 + (lane >> 4) * 8 + j;
    int co = cot * 16 + (lane & 15);
    const float* w = (s == 0) ? w1 : (s == 1) ? w2 : w3;
    wfrag[e] = (bf16_t)w[k * 4096 + c * 64 + co];
  } else {
    int ef = e - 110592;
    int k = ef >> 14, r2 = ef & 16383;
    int kk8 = r2 >> 11, r3 = r2 & 2047;
    int cot = r3 >> 9, r4 = r3 & 511;
    int lane = r4 >> 3, j = r4 & 7;
    int c  = kk8 * 32 + (lane >> 4) * 8 + j;   // 0..255
    int co = cot * 16 + (lane & 15);
    wfrag[e] = (bf16_t)wf[k * 16384 + c * 64 + co];
  }
}

// KK: number of 32-ch K-slices per neighbor (2 = 64ch, 8 = 256ch)
// MODE 0: branch conv (same-seg mask + dilation) -> bf16 outh slice
// MODE 1: final conv, out = acc + bias
// MODE 2: final conv accumulate pass (fallback), out += acc
//
// Block = 256 points (4 waves x 64 rows each, 4 row-tiles of 16 per wave).
// Each weight fragment is loaded ONCE per wave and reused for 4 row-tiles in
// registers -> L1/TCP traffic per output row drops 4x vs the 16-row layout
// (the previous version streamed the full weight set per 16 rows and was
// TCP-throughput-bound: FETCH dropped 2.8x with no time change).
template <int KK, int MODE>
__launch_bounds__(256)
__global__ void conv_mfma(const bf16_t* __restrict__ A, int astride,
                          const bf16_t* __restrict__ wfrag, int wkstride,
                          const int* __restrict__ indices,
                          const int* __restrict__ seg,
                          const int* __restrict__ idx_map,
                          const int* __restrict__ dseg,
                          const int* __restrict__ ord,
                          float* __restrict__ outf,
                          bf16_t* __restrict__ outh, int hstride, int hoff,
                          const float* __restrict__ bias) {
  __shared__ int s_nbr[9 * 256];
  __shared__ int s_pt[256];
  const int tid = threadIdx.x;
  int bid = blockIdx.x;
  // XCD-chunk swizzle (bijective: gridDim.x == 1024, 1024 % 8 == 0)
  if (ord) bid = (bid & 7) * ((int)gridDim.x >> 3) + (bid >> 3);
  const int pt0 = bid * 256;

  {
    int pt = ord ? ord[pt0 + tid] : (pt0 + tid);
    s_pt[tid] = pt;
    int b = indices[pt * 3], y = indices[pt * 3 + 1], x = indices[pt * 3 + 2];
    int sg = 0, d = 1;
    if (MODE == 0) { sg = seg[pt]; d = dseg[sg]; }
#pragma unroll
    for (int k = 0; k < 9; ++k) {
      int ky = (k / 3) - 1, kx = (k % 3) - 1;
      int ny = y + ky * d, nx = x + kx * d;
      int nbr = N_PTS;                         // sentinel zero row
      if (ny >= 0 && ny < H_DIM && nx >= 0 && nx < W_DIM) {
        int v = idx_map[(b * H_DIM + ny) * W_DIM + nx];
        if (v >= 0) {                          // packed (seg<<18)|idx
          if (MODE == 0) nbr = ((v >> 18) == sg) ? (v & 0x3FFFF) : N_PTS;
          else           nbr = v & 0x3FFFF;
        }
      }
      s_nbr[k * 256 + tid] = nbr;
    }
  }
  __syncthreads();

  const int lane = tid & 63;
  const int wv = tid >> 6;
  const int m = lane & 15;
  const int quad = lane >> 4;
  const int rbase = wv * 64 + m;               // + rt*16 -> A-gather row

  f32x4 acc[4][4];                             // [rt][cot]
#pragma unroll
  for (int rt = 0; rt < 4; ++rt)
#pragma unroll
    for (int c = 0; c < 4; ++c) {
      acc[rt][c][0] = 0.f; acc[rt][c][1] = 0.f;
      acc[rt][c][2] = 0.f; acc[rt][c][3] = 0.f;
    }

  if constexpr (KK == 2) {
#pragma unroll
    for (int k = 0; k < 9; ++k) {
      const int* sn = s_nbr + k * 256 + rbase;
      const bf16_t* a0p = A + (size_t)sn[0]  * astride + quad * 8;
      const bf16_t* a1p = A + (size_t)sn[16] * astride + quad * 8;
      const bf16_t* a2p = A + (size_t)sn[32] * astride + quad * 8;
      const bf16_t* a3p = A + (size_t)sn[48] * astride + quad * 8;
      const bf16_t* wk = wfrag + k * wkstride + lane * 8;
#pragma unroll
      for (int kk = 0; kk < 2; ++kk) {
        bf16x8 w0 = *(const bf16x8*)(wk + kk * 2048);
        bf16x8 w1 = *(const bf16x8*)(wk + kk * 2048 + 512);
        bf16x8 w2 = *(const bf16x8*)(wk + kk * 2048 + 1024);
        bf16x8 w3 = *(const bf16x8*)(wk + kk * 2048 + 1536);
        bf16x8 a0 = *(const bf16x8*)(a0p + kk * 32);
        bf16x8 a1 = *(const bf16x8*)(a1p + kk * 32);
        bf16x8 a2 = *(const bf16x8*)(a2p + kk * 32);
        bf16x8 a3 = *(const bf16x8*)(a3p + kk * 32);
        acc[0][0] = __builtin_amdgcn_mfma_f32_16x16x32_bf16(a0, w0, acc[0][0], 0, 0, 0);
        acc[0][1] = __builtin_amdgcn_mfma_f32_16x16x32_bf16(a0, w1, acc[0][1], 0, 0, 0);
        acc[0][2] = __builtin_amdgcn_mfma_f32_16x16x32_bf16(a0, w2, acc[0][2], 0, 0, 0);
        acc[0][3] = __builtin_amdgcn_mfma_f32_16x16x32_bf16(a0, w3, acc[0][3], 0, 0, 0);
        acc[1][0] = __builtin_amdgcn_mfma_f32_16x16x32_bf16(a1, w0, acc[1][0], 0, 0, 0);
        acc[1][1] = __builtin_amdgcn_mfma_f32_16x16x32_bf16(a1, w1, acc[1][1], 0, 0, 0);
        acc[1][2] = __builtin_amdgcn_mfma_f32_16x16x32_bf16(a1, w2, acc[1][2], 0, 0, 0);
        acc[1][3] = __builtin_amdgcn_mfma_f32_16x16x32_bf16(a1, w3, acc[1][3], 0, 0, 0);
        acc[2][0] = __builtin_amdgcn_mfma_f32_16x16x32_bf16(a2, w0, acc[2][0], 0, 0, 0);
        acc[2][1] = __builtin_amdgcn_mfma_f32_16x16x32_bf16(a2, w1, acc[2][1], 0, 0, 0);
        acc[2][2] = __builtin_amdgcn_mfma_f32_16x16x32_bf16(a2, w2, acc[2][2], 0, 0, 0);
        acc[2][3] = __builtin_amdgcn_mfma_f32_16x16x32_bf16(a2, w3, acc[2][3], 0, 0, 0);
        acc[3][0] = __builtin_amdgcn_mfma_f32_16x16x32_bf16(a3, w0, acc[3][0], 0, 0, 0);
        acc[3][1] = __builtin_amdgcn_mfma_f32_16x16x32_bf16(a3, w1, acc[3][1], 0, 0, 0);
        acc[3][2] = __builtin_amdgcn_mfma_f32_16x16x32_bf16(a3, w2, acc[3][2], 0, 0, 0);
        acc[3][3] = __builtin_amdgcn_mfma_f32_16x16x32_bf16(a3, w3, acc[3][3], 0, 0, 0);
      }
    }
  } else {
    // KK == 8: k-loop rolled (code size), neighbor indices prefetched one k ahead
    int nbr0 = s_nbr[rbase], nbr1 = s_nbr[rbase + 16];
    int nbr2 = s_nbr[rbase + 32], nbr3 = s_nbr[rbase + 48];
    for (int k = 0; k < 9; ++k) {
      int nn0 = 0, nn1 = 0, nn2 = 0, nn3 = 0;
      if (k < 8) {
        const int* sn = s_nbr + (k + 1) * 256 + rbase;
        nn0 = sn[0]; nn1 = sn[16]; nn2 = sn[32]; nn3 = sn[48];
      }
      const bf16_t* a0p = A + (size_t)nbr0 * astride + quad * 8;
      const bf16_t* a1p = A + (size_t)nbr1 * astride + quad * 8;
      const bf16_t* a2p = A + (size_t)nbr2 * astride + quad * 8;
      const bf16_t* a3p = A + (size_t)nbr3 * astride + quad * 8;
      const bf16_t* wk = wfrag + k * wkstride + lane * 8;
#pragma unroll
      for (int kk = 0; kk < 8; ++kk) {
        bf16x8 w0 = *(const bf16x8*)(wk + kk * 2048);
        bf16x8 w1 = *(const bf16x8*)(wk + kk * 2048 + 512);
        bf16x8 w2 = *(const bf16x8*)(wk + kk * 2048 + 1024);
        bf16x8 w3 = *(const bf16x8*)(wk + kk * 2048 + 1536);
        bf16x8 a0 = *(const bf16x8*)(a0p + kk * 32);
        bf16x8 a1 = *(const bf16x8*)(a1p + kk * 32);
        bf16x8 a2 = *(const bf16x8*)(a2p + kk * 32);
        bf16x8 a3 = *(const bf16x8*)(a3p + kk * 32);
        acc[0][0] = __builtin_amdgcn_mfma_f32_16x16x32_bf16(a0, w0, acc[0][0], 0, 0, 0);
        acc[0][1] = __builtin_amdgcn_mfma_f32_16x16x32_bf16(a0, w1, acc[0][1], 0, 0, 0);
        acc[0][2] = __builtin_amdgcn_mfma_f32_16x16x32_bf16(a0, w2, acc[0][2], 0, 0, 0);
        acc[0][3] = __builtin_amdgcn_mfma_f32_16x16x32_bf16(a0, w3, acc[0][3], 0, 0, 0);
        acc[1][0] = __builtin_amdgcn_mfma_f32_16x16x32_bf16(a1, w0, acc[1][0], 0, 0, 0);
        acc[1][1] = __builtin_amdgcn_mfma_f32_16x16x32_bf16(a1, w1, acc[1][1], 0, 0, 0);
        acc[1][2] = __builtin_amdgcn_mfma_f32_16x16x32_bf16(a1, w2, acc[1][2], 0, 0, 0);
        acc[1][3] = __builtin_amdgcn_mfma_f32_16x16x32_bf16(a1, w3, acc[1][3], 0, 0, 0);
        acc[2][0] = __builtin_amdgcn_mfma_f32_16x16x32_bf16(a2, w0, acc[2][0], 0, 0, 0);
        acc[2][1] = __builtin_amdgcn_mfma_f32_16x16x32_bf16(a2, w1, acc[2][1], 0, 0, 0);
        acc[2][2] = __builtin_amdgcn_mfma_f32_16x16x32_bf16(a2, w2, acc[2][2], 0, 0, 0);
        acc[2][3] = __builtin_amdgcn_mfma_f32_16x16x32_bf16(a2, w3, acc[2][3], 0, 0, 0);
        acc[3][0] = __builtin_amdgcn_mfma_f32_16x16x32_bf16(a3, w0, acc[3][0], 0, 0, 0);
        acc[3][1] = __builtin_amdgcn_mfma_f32_16x16x32_bf16(a3, w1, acc[3][1], 0, 0, 0);
        acc[3][2] = __builtin_amdgcn_mfma_f32_16x16x32_bf16(a3, w2, acc[3][2], 0, 0, 0);
        acc[3][3] = __builtin_amdgcn_mfma_f32_16x16x32_bf16(a3, w3, acc[3][3], 0, 0, 0);
      }
      nbr0 = nn0; nbr1 = nn1; nbr2 = nn2; nbr3 = nn3;
    }
  }

#pragma unroll
  for (int rt = 0; rt < 4; ++rt) {
#pragma unroll
    for (int reg = 0; reg < 4; ++reg) {
      int r = wv * 64 + rt * 16 + quad * 4 + reg;
      int pt = s_pt[r];
#pragma unroll
      for (int cot = 0; cot < 4; ++cot) {
        int col = cot * 16 + m;
        float v = acc[rt][cot][reg];
        if (MODE == 0)      outh[(size_t)pt * hstride + hoff + col] = (bf16_t)v;
        else if (MODE == 1) outf[(size_t)pt * 64 + col] = v + bias[col];
        else                outf[(size_t)pt * 64 + col] += v;
      }
    }
  }
}

__global__ void stats_kernel(const bf16_t* __restrict__ h, int stride, int off,
                             const int* __restrict__ seg,
                             float* __restrict__ sums, float* __restrict__ sumsq) {
  int tid = threadIdx.x;
  int co = tid & 63, pr = tid >> 6;
  int base = blockIdx.x * 1024;
  float s = 0.f, s2 = 0.f;
  int cur = seg[base];
  for (int i = pr; i < 1024; i += 4) {
    int pt = base + i;
    int sg = seg[pt];
    float v = (float)h[(size_t)pt * stride + off + co];
    if (sg != cur) {
      atomicAdd(&sums[cur * 64 + co], s);
      atomicAdd(&sumsq[cur * 64 + co], s2);
      s = 0.f; s2 = 0.f; cur = sg;
    }
    s += v; s2 += v * v;
  }
  atomicAdd(&sums[cur * 64 + co], s);
  atomicAdd(&sumsq[cur * 64 + co], s2);
}

__global__ void params_kernel(const int* __restrict__ cnt, const float* __restrict__ sums,
                              const float* __restrict__ sumsq,
                              float* __restrict__ pA, float* __restrict__ pB) {
  int t = blockIdx.x * 256 + threadIdx.x;
  if (t < 1024) {
    int sgi = t >> 6;
    float c = (float)cnt[sgi];
    float a = 0.f, b = 0.f;
    if (c > 0.f) {
      float mean = sums[t] / c;
      float var = sumsq[t] / c - mean * mean;
      float inv = rsqrtf(var + EPS_V);
      a = inv; b = -mean * inv;
    }
    pA[t] = a; pB[t] = b;
  }
}

__global__ void norm_kernel(bf16_t* __restrict__ h, int stride, int off,
                            const int* __restrict__ seg,
                            const float* __restrict__ pA, const float* __restrict__ pB) {
  int i = blockIdx.x * 256 + threadIdx.x;   // N*16
  int pt = i >> 4;
  int cg = (i & 15) * 4;
  int sg = seg[pt];
  bf16_t* p = h + (size_t)pt * stride + off + cg;
  union { bf16_t hh[4]; uint2 u; } v;
  v.u = *(uint2*)p;
#pragma unroll
  for (int j = 0; j < 4; ++j) {
    float f = (float)v.hh[j] * pA[sg * 64 + cg + j] + pB[sg * 64 + cg + j];
    v.hh[j] = (bf16_t)fmaxf(f, 0.f);
  }
  *(uint2*)p = v.u;
}

extern "C" void kernel_launch(void* const* d_in, const int* in_sizes, int n_in,
                              void* d_out, int out_size, void* d_ws, size_t ws_size,
                              hipStream_t stream) {
  const float* feats   = (const float*)d_in[0];
  const int*   indices = (const int*)d_in[1];
  const int*   seg     = (const int*)d_in[2];
  const float* w1 = (const float*)d_in[3];
  const float* w2 = (const float*)d_in[5];
  const float* w3 = (const float*)d_in[7];
  const float* wf = (const float*)d_in[9];
  const float* bf_ = (const float*)d_in[10];
  float* out = (float*)d_out;

  char* ws = (char*)d_ws;
  const bool sorted = (ws_size >= 140200000ull);
  const bool fused  = sorted || (ws_size >= 139000000ull);

  int* idx_map = (int*)(ws + 0);
  hipMemsetAsync(idx_map, 0xFF, 4194304, stream);

  if (fused) {
    bf16_t* cat   = (bf16_t*)(ws + 4194304);           // (N+1) x 256
    bf16_t* wfrag = (bf16_t*)(ws + 138412544);
    float*  stats = (float*)(ws + 138928640);
    int* cnt  = (int*)stats;
    int* ymin = (int*)(stats + 16);
    int* ymax = (int*)(stats + 32);
    int* xmin = (int*)(stats + 48);
    int* xmax = (int*)(stats + 64);
    int* dseg = (int*)(stats + 80);
    float* sums  = stats + 128;
    float* sumsq = stats + 3200;
    float* pA    = stats + 6272;
    float* pB    = stats + 9344;
    int* hist   = sorted ? (int*)(stats + 12416) : nullptr;
    int* cursor = sorted ? hist + 4096 : nullptr;
    int* ord    = sorted ? hist + 8192 : nullptr;      // int[N]

    hipMemsetAsync(cat + (size_t)N_PTS * 256, 0, 512, stream);   // sentinel row
    init_kernel<<<1, 256, 0, stream>>>(cnt, ymin, ymax, xmin, xmax, sums, sumsq, hist);
    scatter_kernel<<<N_PTS / 256, 256, 0, stream>>>(indices, seg, idx_map, cnt, ymin, ymax, xmin, xmax, hist);
    dilation_kernel<<<1, 64, 0, stream>>>(ymin, ymax, xmin, xmax, cnt, dseg);
    if (sorted) {
      scan_kernel<<<1, 256, 0, stream>>>(hist, cursor);
      rank_kernel<<<N_PTS / 256, 256, 0, stream>>>(indices, cursor, ord);
    }
    convert_kernel<<<16384, 256, 0, stream>>>((const float4*)feats, cat, 256);
    repack_kernel<<<1008, 256, 0, stream>>>(w1, w2, w3, wf, wfrag);

    for (int r = 0; r < 3; ++r) {
      conv_mfma<2, 0><<<1024, 256, 0, stream>>>(cat, 256, wfrag + (size_t)r * 36864, 4096,
                                                indices, seg, idx_map, dseg + r * 16, ord,
                                                nullptr, cat, 256, (r + 1) * 64, nullptr);
      stats_kernel<<<256, 256, 0, stream>>>(cat, 256, (r + 1) * 64, seg,
                                            sums + r * 1024, sumsq + r * 1024);
      params_kernel<<<4, 256, 0, stream>>>(cnt, sums + r * 1024, sumsq + r * 1024,
                                           pA + r * 1024, pB + r * 1024);
      norm_kernel<<<16384, 256, 0, stream>>>(cat, 256, (r + 1) * 64, seg,
                                             pA + r * 1024, pB + r * 1024);
    }
    // fused final conv: K = 256 in one pass
    conv_mfma<8, 1><<<1024, 256, 0, stream>>>(cat, 256, wfrag + 110592, 16384,
                                              indices, seg, idx_map, nullptr, ord,
                                              out, nullptr, 0, 0, bf_);
  } else {
    bf16_t* feats_bf = (bf16_t*)(ws + 4194304);        // (N+1) x 64
    bf16_t* h_bf     = (bf16_t*)(ws + 37748864);       // (N+1) x 64
    bf16_t* wfrag    = (bf16_t*)(ws + 71303424);
    float*  stats    = (float*)(ws + 71819520);
    int* cnt  = (int*)stats;
    int* ymin = (int*)(stats + 16);
    int* ymax = (int*)(stats + 32);
    int* xmin = (int*)(stats + 48);
    int* xmax = (int*)(stats + 64);
    int* dseg = (int*)(stats + 80);
    float* sums  = stats + 128;
    float* sumsq = stats + 3200;
    float* pA    = stats + 6272;
    float* pB    = stats + 9344;

    hipMemsetAsync(feats_bf + (size_t)N_PTS * 64, 0, 128, stream);
    hipMemsetAsync(h_bf + (size_t)N_PTS * 64, 0, 128, stream);
    init_kernel<<<1, 256, 0, stream>>>(cnt, ymin, ymax, xmin, xmax, sums, sumsq, nullptr);
    scatter_kernel<<<N_PTS / 256, 256, 0, stream>>>(indices, seg, idx_map, cnt, ymin, ymax, xmin, xmax, nullptr);
    dilation_kernel<<<1, 64, 0, stream>>>(ymin, ymax, xmin, xmax, cnt, dseg);
    convert_kernel<<<16384, 256, 0, stream>>>((const float4*)feats, feats_bf, 64);
    repack_kernel<<<1008, 256, 0, stream>>>(w1, w2, w3, wf, wfrag);

    // final conv pass 0: features slice (init with bias), uses fused-wfrag slice p=0
    conv_mfma<2, 1><<<1024, 256, 0, stream>>>(feats_bf, 64, wfrag + 110592, 16384,
                                              indices, seg, idx_map, nullptr, nullptr,
                                              out, nullptr, 0, 0, bf_);
    for (int r = 0; r < 3; ++r) {
      conv_mfma<2, 0><<<1024, 256, 0, stream>>>(feats_bf, 64, wfrag + (size_t)r * 36864, 4096,
                                                indices, seg, idx_map, dseg + r * 16, nullptr,
                                                nullptr, h_bf, 64, 0, nullptr);
      stats_kernel<<<256, 256, 0, stream>>>(h_bf, 64, 0, seg, sums + r * 1024, sumsq + r * 1024);
      params_kernel<<<4, 256, 0, stream>>>(cnt, sums + r * 1024, sumsq + r * 1024,
                                           pA + r * 1024, pB + r * 1024);
      norm_kernel<<<16384, 256, 0, stream>>>(h_bf, 64, 0, seg, pA + r * 1024, pB + r * 1024);
      conv_mfma<2, 2><<<1024, 256, 0, stream>>>(h_bf, 64, wfrag + 110592 + (size_t)(r + 1) * 4096, 16384,
                                                indices, seg, idx_map, nullptr, nullptr,
                                                out, nullptr, 0, 0, nullptr);
    }
  }
}

// Round 3
// 705.892 us; speedup vs baseline: 1.2063x; 1.1135x over previous
//
#include <hip/hip_runtime.h>
#include <hip/hip_bf16.h>
#include <stdint.h>

#define N_PTS   262144
#define H_DIM   512
#define W_DIM   512
#define N_SEG   16
#define EPS_V   1e-5f

typedef __bf16 bf16_t;
typedef __bf16 bf16x8 __attribute__((ext_vector_type(8)));
typedef float  f32x4  __attribute__((ext_vector_type(4)));

// async global->LDS, 16B per lane. LDS dest must be wave-uniform base + lane*16:
// callers pass l = base + tid*8 elems, so lane pointers are consecutive 16B. OK.
__device__ __forceinline__ void gl_lds16(const bf16_t* g, bf16_t* l) {
  __builtin_amdgcn_global_load_lds(
      (const __attribute__((address_space(1))) unsigned int*)g,
      (__attribute__((address_space(3))) unsigned int*)l, 16, 0, 0);
}

// ------------- workspace layouts -------------
// FUSED+SORT (ws >= ~140.2 MB):
//   idx_map int[4*512*512]            @ 0            (4194304)   packed (seg<<18)|idx, -1 empty
//   cat     bf16[(N+1)*256]           @ 4194304      (134218240) [feat|h1|h2|h3], row N = zeros
//   wfrag   bf16[258048]              @ 138412544    (516096)
//   stats   float[12416]              @ 138928640    (49664)
//   hist    int[4096] / cursor int[4096] / ord int[N]
// FUSED (ws >= 139 MB): same minus hist/cursor/ord (ord = nullptr)
// FALLBACK: as before at 72 MB.
// stats block (floats): cnt[16]@0 ymin@16 ymax@32 xmin@48 xmax@64 dseg[48]@80
//   sums[3*1024]@128 sumsq[3*1024]@3200 pA[3*1024]@6272 pB[3*1024]@9344

__global__ void init_kernel(int* cnt, int* ymin, int* ymax, int* xmin, int* xmax,
                            float* sums, float* sumsq, int* hist) {
  int t = threadIdx.x;
  if (t < N_SEG) {
    cnt[t] = 0;
    ymin[t] = 0x7fffffff; ymax[t] = (int)0x80000000;
    xmin[t] = 0x7fffffff; xmax[t] = (int)0x80000000;
  }
  for (int i = t; i < 3 * 1024; i += 256) { sums[i] = 0.f; sumsq[i] = 0.f; }
  if (hist) for (int i = t; i < 4096; i += 256) hist[i] = 0;
}

__global__ void scatter_kernel(const int* __restrict__ indices,
                               const int* __restrict__ seg,
                               int* __restrict__ idx_map,
                               int* __restrict__ cnt,
                               int* __restrict__ ymin, int* __restrict__ ymax,
                               int* __restrict__ xmin, int* __restrict__ xmax,
                               int* __restrict__ hist) {
  __shared__ int lc[N_SEG], ly0[N_SEG], ly1[N_SEG], lx0[N_SEG], lx1[N_SEG];
  int tid = threadIdx.x;
  if (tid < N_SEG) {
    lc[tid] = 0;
    ly0[tid] = 0x7fffffff; ly1[tid] = (int)0x80000000;
    lx0[tid] = 0x7fffffff; lx1[tid] = (int)0x80000000;
  }
  __syncthreads();
  int i = blockIdx.x * 256 + tid;
  int b = indices[i * 3], y = indices[i * 3 + 1], x = indices[i * 3 + 2];
  int s = seg[i];
  idx_map[(b * H_DIM + y) * W_DIM + x] = (s << 18) | i;   // packed seg+idx
  atomicAdd(&lc[s], 1);
  atomicMin(&ly0[s], y); atomicMax(&ly1[s], y);
  atomicMin(&lx0[s], x); atomicMax(&lx1[s], x);
  if (hist) {
    int key = (b << 10) | ((y >> 4) << 5) | (x >> 4);     // 4096 spatial tiles
    atomicAdd(&hist[key], 1);
  }
  __syncthreads();
  if (tid < N_SEG && lc[tid] > 0) {
    atomicAdd(&cnt[tid], lc[tid]);
    atomicMin(&ymin[tid], ly0[tid]); atomicMax(&ymax[tid], ly1[tid]);
    atomicMin(&xmin[tid], lx0[tid]); atomicMax(&xmax[tid], lx1[tid]);
  }
}

// exclusive prefix sum of hist[4096] -> cursor[4096]
__global__ void scan_kernel(const int* __restrict__ hist, int* __restrict__ cursor) {
  __shared__ int s[256];
  int t = threadIdx.x;
  int base = t * 16;
  int loc[16];
  int acc = 0;
#pragma unroll
  for (int j = 0; j < 16; ++j) { loc[j] = acc; acc += hist[base + j]; }
  s[t] = acc;
  __syncthreads();
  for (int o = 1; o < 256; o <<= 1) {
    int v = (t >= o) ? s[t - o] : 0;
    __syncthreads();
    s[t] += v;
    __syncthreads();
  }
  int pre = (t == 0) ? 0 : s[t - 1];
#pragma unroll
  for (int j = 0; j < 16; ++j) cursor[base + j] = pre + loc[j];
}

__global__ void rank_kernel(const int* __restrict__ indices,
                            int* __restrict__ cursor, int* __restrict__ ord) {
  int i = blockIdx.x * 256 + threadIdx.x;
  int b = indices[i * 3], y = indices[i * 3 + 1], x = indices[i * 3 + 2];
  int key = (b << 10) | ((y >> 4) << 5) | (x >> 4);
  int pos = atomicAdd(&cursor[key], 1);
  ord[pos] = i;
}

__global__ void dilation_kernel(const int* ymin, const int* ymax,
                                const int* xmin, const int* xmax,
                                const int* cnt, int* dseg) {
  int t = threadIdx.x;
  if (t < 48) {
    int r = t >> 4, s = t & 15;
    int rate = (r == 0) ? 1 : (r == 1) ? 3 : 5;
    int d = 1;
    if (cnt[s] > 0) {
      float hr = (float)(ymax[s] - ymin[s]) * (1.0f / H_DIM);
      float wr = (float)(xmax[s] - xmin[s]) * (1.0f / W_DIM);
      d = (int)ceilf(fmaxf(hr, wr) * (float)rate);
      if (d < 1) d = 1;
    }
    dseg[t] = d;
  }
}

// features fp32 -> bf16 rows of a strided buffer
__global__ void convert_kernel(const float4* __restrict__ in, bf16_t* __restrict__ dst,
                               int stride) {
  int i = blockIdx.x * 256 + threadIdx.x;   // N*16
  int pt = i >> 4, g = i & 15;
  float4 v = in[i];
  union { bf16_t h[4]; uint2 u; } o;
  o.h[0] = (bf16_t)v.x; o.h[1] = (bf16_t)v.y;
  o.h[2] = (bf16_t)v.z; o.h[3] = (bf16_t)v.w;
  *(uint2*)(dst + (size_t)pt * stride + g * 4) = o.u;
}

// wfrag: [0,110592): branch r in {0,1,2} at r*36864, layout [k][kk2][cot][lane][j]
//        [110592,258048): fused final, layout [k][kk8][cot][lane][j], kk8=0..7
__global__ void repack_kernel(const float* __restrict__ w1, const float* __restrict__ w2,
                              const float* __restrict__ w3, const float* __restrict__ wf,
                              bf16_t* __restrict__ wfrag) {
  int e = blockIdx.x * 256 + threadIdx.x;   // < 258048
  if (e < 110592) {
    int s = e / 36864, rem = e % 36864;
    int k = rem >> 12, r2 = rem & 4095;
    int kk = r2 >> 11, r3 = r2 & 2047;
    int cot = r3 >> 9, r4 = r3 & 511;
    int lane = r4 >> 3, j = r4 & 7;
    int c  = kk * 32 + (lane >> 4) * 8 + j;
    int co = cot * 16 + (lane & 15);
    const float* w = (s == 0) ? w1 : (s == 1) ? w2 : w3;
    wfrag[e] = (bf16_t)w[k * 4096 + c * 64 + co];
  } else {
    int ef = e - 110592;
    int k = ef >> 14, r2 = ef & 16383;
    int kk8 = r2 >> 11, r3 = r2 & 2047;
    int cot = r3 >> 9, r4 = r3 & 511;
    int lane = r4 >> 3, j = r4 & 7;
    int c  = kk8 * 32 + (lane >> 4) * 8 + j;   // 0..255
    int co = cot * 16 + (lane & 15);
    wfrag[e] = (bf16_t)wf[k * 16384 + c * 64 + co];
  }
}

#define MF(ar, wr, i, j) \
  acc[i][j] = __builtin_amdgcn_mfma_f32_16x16x32_bf16(ar, wr, acc[i][j], 0, 0, 0)
#define MF16(A0, A1, A2, A3, W0, W1, W2, W3) \
  MF(A0, W0, 0, 0); MF(A0, W1, 0, 1); MF(A0, W2, 0, 2); MF(A0, W3, 0, 3); \
  MF(A1, W0, 1, 0); MF(A1, W1, 1, 1); MF(A1, W2, 1, 2); MF(A1, W3, 1, 3); \
  MF(A2, W0, 2, 0); MF(A2, W1, 2, 1); MF(A2, W2, 2, 2); MF(A2, W3, 2, 3); \
  MF(A3, W0, 3, 0); MF(A3, W1, 3, 1); MF(A3, W2, 3, 2); MF(A3, W3, 3, 3)

// KK: number of 32-ch K-slices per neighbor (2 = 64ch, 8 = 256ch)
// MODE 0: branch conv (same-seg mask + dilation) -> bf16 outh slice
// MODE 1: final conv, out = acc + bias
// MODE 2: final conv accumulate pass (fallback), out += acc
//
// Block = 256 points (4 waves x 64 rows each, 4 row-tiles of 16 per wave).
// Weights are async-staged (global_load_lds) into a double-buffered LDS slice
// one phase ahead of use: weight reads become short-latency ds_read_b128 and
// the per-phase global chain is just the 8 batched A-gathers. (Round-2 was
// latency-bound: all pipes <=30% of ceiling at 22% occupancy, VGPR 76 kept
// only ~2-4 loads in flight.)
template <int KK, int MODE>
__launch_bounds__(256, 3)
__global__ void conv_mfma(const bf16_t* __restrict__ A, int astride,
                          const bf16_t* __restrict__ wfrag, int wkstride,
                          const int* __restrict__ indices,
                          const int* __restrict__ seg,
                          const int* __restrict__ idx_map,
                          const int* __restrict__ dseg,
                          const int* __restrict__ ord,
                          float* __restrict__ outf,
                          bf16_t* __restrict__ outh, int hstride, int hoff,
                          const float* __restrict__ bias) {
  constexpr int WELEM = (KK == 8) ? 8192 : 4096;     // elems per LDS w-buffer
  constexpr int SWEEPS = (KK == 8) ? 4 : 2;          // 256 thr x 16B sweeps
  __shared__ int s_nbr[9 * 256];
  __shared__ int s_pt[256];
  __shared__ bf16_t s_w[2][WELEM];
  const int tid = threadIdx.x;
  int bid = blockIdx.x;
  // XCD-chunk swizzle (bijective: gridDim.x == 1024, 1024 % 8 == 0)
  if (ord) bid = (bid & 7) * ((int)gridDim.x >> 3) + (bid >> 3);
  const int pt0 = bid * 256;

  {
    int pt = ord ? ord[pt0 + tid] : (pt0 + tid);
    s_pt[tid] = pt;
    int b = indices[pt * 3], y = indices[pt * 3 + 1], x = indices[pt * 3 + 2];
    int sg = 0, d = 1;
    if (MODE == 0) { sg = seg[pt]; d = dseg[sg]; }
#pragma unroll
    for (int k = 0; k < 9; ++k) {
      int ky = (k / 3) - 1, kx = (k % 3) - 1;
      int ny = y + ky * d, nx = x + kx * d;
      int nbr = N_PTS;                         // sentinel zero row
      if (ny >= 0 && ny < H_DIM && nx >= 0 && nx < W_DIM) {
        int v = idx_map[(b * H_DIM + ny) * W_DIM + nx];
        if (v >= 0) {                          // packed (seg<<18)|idx
          if (MODE == 0) nbr = ((v >> 18) == sg) ? (v & 0x3FFFF) : N_PTS;
          else           nbr = v & 0x3FFFF;
        }
      }
      s_nbr[k * 256 + tid] = nbr;
    }
  }

  // phase ph: KK=2 -> slice k=ph (8 KB); KK=8 -> half-slice (k=ph>>1, half=ph&1, 16 KB)
  auto stage = [&](int ph, int buf) {
    const bf16_t* src;
    if constexpr (KK == 8) src = wfrag + (size_t)(ph >> 1) * wkstride + (ph & 1) * 8192;
    else                   src = wfrag + (size_t)ph * wkstride;
#pragma unroll
    for (int s = 0; s < SWEEPS; ++s) {
      int off = s * 2048 + tid * 8;
      gl_lds16(src + off, &s_w[buf][off]);
    }
  };

  stage(0, 0);
  __syncthreads();   // covers s_nbr/s_pt writes AND drains stage(0) (vmcnt)

  const int lane = tid & 63;
  const int wv = tid >> 6;
  const int m = lane & 15;
  const int quad = lane >> 4;
  const int rbase = wv * 64 + m;               // + rt*16 -> A-gather row

  f32x4 acc[4][4];                             // [rt][cot]
#pragma unroll
  for (int rt = 0; rt < 4; ++rt)
#pragma unroll
    for (int c = 0; c < 4; ++c) {
      acc[rt][c][0] = 0.f; acc[rt][c][1] = 0.f;
      acc[rt][c][2] = 0.f; acc[rt][c][3] = 0.f;
    }

  if constexpr (KK == 2) {
    for (int k = 0; k < 9; ++k) {
      const int cur = k & 1;
      if (k < 8) stage(k + 1, cur ^ 1);
      const int* sn = s_nbr + k * 256 + rbase;
      const bf16_t* a0p = A + (size_t)sn[0]  * astride + quad * 8;
      const bf16_t* a1p = A + (size_t)sn[16] * astride + quad * 8;
      const bf16_t* a2p = A + (size_t)sn[32] * astride + quad * 8;
      const bf16_t* a3p = A + (size_t)sn[48] * astride + quad * 8;
      bf16x8 a00 = *(const bf16x8*)(a0p), a01 = *(const bf16x8*)(a0p + 32);
      bf16x8 a10 = *(const bf16x8*)(a1p), a11 = *(const bf16x8*)(a1p + 32);
      bf16x8 a20 = *(const bf16x8*)(a2p), a21 = *(const bf16x8*)(a2p + 32);
      bf16x8 a30 = *(const bf16x8*)(a3p), a31 = *(const bf16x8*)(a3p + 32);
      const bf16_t* wl = &s_w[cur][lane * 8];
      bf16x8 w00 = *(const bf16x8*)(wl +    0), w01 = *(const bf16x8*)(wl +  512);
      bf16x8 w02 = *(const bf16x8*)(wl + 1024), w03 = *(const bf16x8*)(wl + 1536);
      bf16x8 w10 = *(const bf16x8*)(wl + 2048), w11 = *(const bf16x8*)(wl + 2560);
      bf16x8 w12 = *(const bf16x8*)(wl + 3072), w13 = *(const bf16x8*)(wl + 3584);
      MF16(a00, a10, a20, a30, w00, w01, w02, w03);
      MF16(a01, a11, a21, a31, w10, w11, w12, w13);
      __syncthreads();   // all waves done with s_w[cur]; stage(k+1) landed
    }
  } else {
    // KK == 8: 18 half-slice phases, 2 kk-pairs per phase
    for (int h = 0; h < 18; ++h) {
      const int cur = h & 1;
      if (h < 17) stage(h + 1, cur ^ 1);
      const int k = h >> 1;
      const int colb = (h & 1) * 128;           // half -> channel offset (elems)
      const int* sn = s_nbr + k * 256 + rbase;
      const bf16_t* a0p = A + (size_t)sn[0]  * astride + quad * 8 + colb;
      const bf16_t* a1p = A + (size_t)sn[16] * astride + quad * 8 + colb;
      const bf16_t* a2p = A + (size_t)sn[32] * astride + quad * 8 + colb;
      const bf16_t* a3p = A + (size_t)sn[48] * astride + quad * 8 + colb;
#pragma unroll
      for (int kp = 0; kp < 2; ++kp) {
        const int cb = kp * 64;
        bf16x8 a00 = *(const bf16x8*)(a0p + cb), a01 = *(const bf16x8*)(a0p + cb + 32);
        bf16x8 a10 = *(const bf16x8*)(a1p + cb), a11 = *(const bf16x8*)(a1p + cb + 32);
        bf16x8 a20 = *(const bf16x8*)(a2p + cb), a21 = *(const bf16x8*)(a2p + cb + 32);
        bf16x8 a30 = *(const bf16x8*)(a3p + cb), a31 = *(const bf16x8*)(a3p + cb + 32);
        const bf16_t* wl = &s_w[cur][kp * 4096 + lane * 8];
        bf16x8 w00 = *(const bf16x8*)(wl +    0), w01 = *(const bf16x8*)(wl +  512);
        bf16x8 w02 = *(const bf16x8*)(wl + 1024), w03 = *(const bf16x8*)(wl + 1536);
        bf16x8 w10 = *(const bf16x8*)(wl + 2048), w11 = *(const bf16x8*)(wl + 2560);
        bf16x8 w12 = *(const bf16x8*)(wl + 3072), w13 = *(const bf16x8*)(wl + 3584);
        MF16(a00, a10, a20, a30, w00, w01, w02, w03);
        MF16(a01, a11, a21, a31, w10, w11, w12, w13);
      }
      __syncthreads();
    }
  }

#pragma unroll
  for (int rt = 0; rt < 4; ++rt) {
#pragma unroll
    for (int reg = 0; reg < 4; ++reg) {
      int r = wv * 64 + rt * 16 + quad * 4 + reg;
      int pt = s_pt[r];
#pragma unroll
      for (int cot = 0; cot < 4; ++cot) {
        int col = cot * 16 + m;
        float v = acc[rt][cot][reg];
        if (MODE == 0)      outh[(size_t)pt * hstride + hoff + col] = (bf16_t)v;
        else if (MODE == 1) outf[(size_t)pt * 64 + col] = v + bias[col];
        else                outf[(size_t)pt * 64 + col] += v;
      }
    }
  }
}

__global__ void stats_kernel(const bf16_t* __restrict__ h, int stride, int off,
                             const int* __restrict__ seg,
                             float* __restrict__ sums, float* __restrict__ sumsq) {
  int tid = threadIdx.x;
  int co = tid & 63, pr = tid >> 6;
  int base = blockIdx.x * 1024;
  float s = 0.f, s2 = 0.f;
  int cur = seg[base];
  for (int i = pr; i < 1024; i += 4) {
    int pt = base + i;
    int sg = seg[pt];
    float v = (float)h[(size_t)pt * stride + off + co];
    if (sg != cur) {
      atomicAdd(&sums[cur * 64 + co], s);
      atomicAdd(&sumsq[cur * 64 + co], s2);
      s = 0.f; s2 = 0.f; cur = sg;
    }
    s += v; s2 += v * v;
  }
  atomicAdd(&sums[cur * 64 + co], s);
  atomicAdd(&sumsq[cur * 64 + co], s2);
}

__global__ void params_kernel(const int* __restrict__ cnt, const float* __restrict__ sums,
                              const float* __restrict__ sumsq,
                              float* __restrict__ pA, float* __restrict__ pB) {
  int t = blockIdx.x * 256 + threadIdx.x;
  if (t < 1024) {
    int sgi = t >> 6;
    float c = (float)cnt[sgi];
    float a = 0.f, b = 0.f;
    if (c > 0.f) {
      float mean = sums[t] / c;
      float var = sumsq[t] / c - mean * mean;
      float inv = rsqrtf(var + EPS_V);
      a = inv; b = -mean * inv;
    }
    pA[t] = a; pB[t] = b;
  }
}

__global__ void norm_kernel(bf16_t* __restrict__ h, int stride, int off,
                            const int* __restrict__ seg,
                            const float* __restrict__ pA, const float* __restrict__ pB) {
  int i = blockIdx.x * 256 + threadIdx.x;   // N*16
  int pt = i >> 4;
  int cg = (i & 15) * 4;
  int sg = seg[pt];
  bf16_t* p = h + (size_t)pt * stride + off + cg;
  union { bf16_t hh[4]; uint2 u; } v;
  v.u = *(uint2*)p;
#pragma unroll
  for (int j = 0; j < 4; ++j) {
    float f = (float)v.hh[j] * pA[sg * 64 + cg + j] + pB[sg * 64 + cg + j];
    v.hh[j] = (bf16_t)fmaxf(f, 0.f);
  }
  *(uint2*)p = v.u;
}

extern "C" void kernel_launch(void* const* d_in, const int* in_sizes, int n_in,
                              void* d_out, int out_size, void* d_ws, size_t ws_size,
                              hipStream_t stream) {
  const float* feats   = (const float*)d_in[0];
  const int*   indices = (const int*)d_in[1];
  const int*   seg     = (const int*)d_in[2];
  const float* w1 = (const float*)d_in[3];
  const float* w2 = (const float*)d_in[5];
  const float* w3 = (const float*)d_in[7];
  const float* wf = (const float*)d_in[9];
  const float* bf_ = (const float*)d_in[10];
  float* out = (float*)d_out;

  char* ws = (char*)d_ws;
  const bool sorted = (ws_size >= 140200000ull);
  const bool fused  = sorted || (ws_size >= 139000000ull);

  int* idx_map = (int*)(ws + 0);
  hipMemsetAsync(idx_map, 0xFF, 4194304, stream);

  if (fused) {
    bf16_t* cat   = (bf16_t*)(ws + 4194304);           // (N+1) x 256
    bf16_t* wfrag = (bf16_t*)(ws + 138412544);
    float*  stats = (float*)(ws + 138928640);
    int* cnt  = (int*)stats;
    int* ymin = (int*)(stats + 16);
    int* ymax = (int*)(stats + 32);
    int* xmin = (int*)(stats + 48);
    int* xmax = (int*)(stats + 64);
    int* dseg = (int*)(stats + 80);
    float* sums  = stats + 128;
    float* sumsq = stats + 3200;
    float* pA    = stats + 6272;
    float* pB    = stats + 9344;
    int* hist   = sorted ? (int*)(stats + 12416) : nullptr;
    int* cursor = sorted ? hist + 4096 : nullptr;
    int* ord    = sorted ? hist + 8192 : nullptr;      // int[N]

    hipMemsetAsync(cat + (size_t)N_PTS * 256, 0, 512, stream);   // sentinel row
    init_kernel<<<1, 256, 0, stream>>>(cnt, ymin, ymax, xmin, xmax, sums, sumsq, hist);
    scatter_kernel<<<N_PTS / 256, 256, 0, stream>>>(indices, seg, idx_map, cnt, ymin, ymax, xmin, xmax, hist);
    dilation_kernel<<<1, 64, 0, stream>>>(ymin, ymax, xmin, xmax, cnt, dseg);
    if (sorted) {
      scan_kernel<<<1, 256, 0, stream>>>(hist, cursor);
      rank_kernel<<<N_PTS / 256, 256, 0, stream>>>(indices, cursor, ord);
    }
    convert_kernel<<<16384, 256, 0, stream>>>((const float4*)feats, cat, 256);
    repack_kernel<<<1008, 256, 0, stream>>>(w1, w2, w3, wf, wfrag);

    for (int r = 0; r < 3; ++r) {
      conv_mfma<2, 0><<<1024, 256, 0, stream>>>(cat, 256, wfrag + (size_t)r * 36864, 4096,
                                                indices, seg, idx_map, dseg + r * 16, ord,
                                                nullptr, cat, 256, (r + 1) * 64, nullptr);
      stats_kernel<<<256, 256, 0, stream>>>(cat, 256, (r + 1) * 64, seg,
                                            sums + r * 1024, sumsq + r * 1024);
      params_kernel<<<4, 256, 0, stream>>>(cnt, sums + r * 1024, sumsq + r * 1024,
                                           pA + r * 1024, pB + r * 1024);
      norm_kernel<<<16384, 256, 0, stream>>>(cat, 256, (r + 1) * 64, seg,
                                             pA + r * 1024, pB + r * 1024);
    }
    // fused final conv: K = 256 in one pass
    conv_mfma<8, 1><<<1024, 256, 0, stream>>>(cat, 256, wfrag + 110592, 16384,
                                              indices, seg, idx_map, nullptr, ord,
                                              out, nullptr, 0, 0, bf_);
  } else {
    bf16_t* feats_bf = (bf16_t*)(ws + 4194304);        // (N+1) x 64
    bf16_t* h_bf     = (bf16_t*)(ws + 37748864);       // (N+1) x 64
    bf16_t* wfrag    = (bf16_t*)(ws + 71303424);
    float*  stats    = (float*)(ws + 71819520);
    int* cnt  = (int*)stats;
    int* ymin = (int*)(stats + 16);
    int* ymax = (int*)(stats + 32);
    int* xmin = (int*)(stats + 48);
    int* xmax = (int*)(stats + 64);
    int* dseg = (int*)(stats + 80);
    float* sums  = stats + 128;
    float* sumsq = stats + 3200;
    float* pA    = stats + 6272;
    float* pB    = stats + 9344;

    hipMemsetAsync(feats_bf + (size_t)N_PTS * 64, 0, 128, stream);
    hipMemsetAsync(h_bf + (size_t)N_PTS * 64, 0, 128, stream);
    init_kernel<<<1, 256, 0, stream>>>(cnt, ymin, ymax, xmin, xmax, sums, sumsq, nullptr);
    scatter_kernel<<<N_PTS / 256, 256, 0, stream>>>(indices, seg, idx_map, cnt, ymin, ymax, xmin, xmax, nullptr);
    dilation_kernel<<<1, 64, 0, stream>>>(ymin, ymax, xmin, xmax, cnt, dseg);
    convert_kernel<<<16384, 256, 0, stream>>>((const float4*)feats, feats_bf, 64);
    repack_kernel<<<1008, 256, 0, stream>>>(w1, w2, w3, wf, wfrag);

    // final conv pass 0: features slice (init with bias), uses fused-wfrag slice p=0
    conv_mfma<2, 1><<<1024, 256, 0, stream>>>(feats_bf, 64, wfrag + 110592, 16384,
                                              indices, seg, idx_map, nullptr, nullptr,
                                              out, nullptr, 0, 0, bf_);
    for (int r = 0; r < 3; ++r) {
      conv_mfma<2, 0><<<1024, 256, 0, stream>>>(feats_bf, 64, wfrag + (size_t)r * 36864, 4096,
                                                indices, seg, idx_map, dseg + r * 16, nullptr,
                                                nullptr, h_bf, 64, 0, nullptr);
      stats_kernel<<<256, 256, 0, stream>>>(h_bf, 64, 0, seg, sums + r * 1024, sumsq + r * 1024);
      params_kernel<<<4, 256, 0, stream>>>(cnt, sums + r * 1024, sumsq + r * 1024,
                                           pA + r * 1024, pB + r * 1024);
      norm_kernel<<<16384, 256, 0, stream>>>(h_bf, 64, 0, seg, pA + r * 1024, pB + r * 1024);
      conv_mfma<2, 2><<<1024, 256, 0, stream>>>(h_bf, 64, wfrag + 110592 + (size_t)(r + 1) * 4096, 16384,
                                                indices, seg, idx_map, nullptr, nullptr,
                                                out, nullptr, 0, 0, nullptr);
    }
  }
}